// Round 13
// baseline (248.740 us; speedup 1.0000x reference)
//
#include <hip/hip_runtime.h>
#include <hip/hip_fp16.h>
#include <cstdint>
#include <cstddef>
#include <cmath>

// ---------------------------------------------------------------------------
// GCN via CSR aggregation:
//   binning: fixed-capacity dst-buckets (256 nodes, CAP=12288) -> k_pass1
//            packs edges into tmp runs -> k_p2 builds rowptr/cnt/dinv + csrc
//   agg: one wave per node, 16 groups of 4 lanes; each group owns one edge,
//        each lane loads one uint4 (16B) of the 64B fp8 row -> one gather
//        instruction covers 16 edges; unroll-2 = 32 edges in flight.
//   xform1/xform2/final: MFMA 16x16x32 f16, B-frags in registers; fp8 message
//   rows packed via v_cvt_pk_fp8_f32 (byte b of uint s = channel s+16b).
//   tmp aliases B2 (dead before first k_agg write).
// ---------------------------------------------------------------------------

#define T1  4096    // edges per pass-1 tile
#define CAP 12288   // bucket capacity (avg 8184, sigma ~90)

typedef _Float16 half8 __attribute__((ext_vector_type(8)));
typedef float f32x4 __attribute__((ext_vector_type(4)));
typedef float f32x2 __attribute__((ext_vector_type(2)));

__global__ __launch_bounds__(512) void k_init(int* __restrict__ cursor1, int NB) {
    int t = threadIdx.x;
    for (int i = t; i < NB; i += 512) cursor1[i] = i * CAP;
}

__global__ __launch_bounds__(256) void k_pass1(const int* __restrict__ src,
        const int* __restrict__ dst, int* __restrict__ cursor1,
        unsigned int* __restrict__ tmp, int E, int NB) {
    __shared__ unsigned int pack[T1];
    __shared__ unsigned short bkt[T1];
    __shared__ int h[512], hs_[512], gbase[512];
    int t = threadIdx.x;
    for (int i = t; i < 512; i += 256) h[i] = 0;
    __syncthreads();
    int base = blockIdx.x * T1;
    int n = min(T1, E - base);
    unsigned int pk[16];
    int bl[16];
    #pragma unroll
    for (int i = 0; i < 16; ++i) {
        int idx = i * 256 + t;
        if (idx < n) {
            int s_ = src[base + idx], d = dst[base + idx];
            int b = d >> 8;
            pk[i] = (unsigned int)s_ | ((unsigned int)(d & 255) << 17);
            int lo = atomicAdd(&h[b], 1);
            bl[i] = (b << 13) | lo;
        } else bl[i] = -1;
    }
    __syncthreads();
    hs_[t] = h[t]; hs_[t + 256] = h[t + 256];
    __syncthreads();
    for (int st = 1; st < 512; st <<= 1) {
        int v0 = (t >= st) ? hs_[t - st] : 0;
        int v1 = (t + 256 >= st) ? hs_[t + 256 - st] : 0;
        __syncthreads();
        hs_[t] += v0; hs_[t + 256] += v1;
        __syncthreads();
    }
    for (int i = t; i < NB; i += 256)
        gbase[i] = h[i] ? atomicAdd(&cursor1[i], h[i]) : 0;
    __syncthreads();
    #pragma unroll
    for (int i = 0; i < 16; ++i) {
        if (bl[i] >= 0) {
            int b = bl[i] >> 13, lo = bl[i] & 8191;
            int slot = hs_[b] - h[b] + lo;
            pack[slot] = pk[i];
            bkt[slot]  = (unsigned short)b;
        }
    }
    __syncthreads();
    for (int s_ = t; s_ < n; s_ += 256) {
        int b = bkt[s_];
        tmp[gbase[b] + (s_ - (hs_[b] - h[b]))] = pack[s_];
    }
}

// per-bucket: histogram -> LDS scan -> rowptr/cnt/dinv -> csrc scatter
__global__ __launch_bounds__(256) void k_p2(const unsigned int* __restrict__ tmp,
        const int* __restrict__ cursor1, int* __restrict__ rowptr,
        int* __restrict__ cnt, int* __restrict__ csrc,
        float* __restrict__ dinv, int N) {
    __shared__ int c[256], cur[256];
    int t = threadIdx.x, b = blockIdx.x;
    c[t] = 0;
    __syncthreads();
    int s0 = b * CAP, s1 = cursor1[b];
    for (int s = s0 + t; s < s1; s += 256)
        atomicAdd(&c[(tmp[s] >> 17) & 255], 1);
    __syncthreads();
    int v = c[t];
    cur[t] = v;
    __syncthreads();
    for (int st = 1; st < 256; st <<= 1) {
        int p = (t >= st) ? cur[t - st] : 0;
        __syncthreads();
        cur[t] += p;
        __syncthreads();
    }
    int rp = s0 + cur[t] - v;     // bucket base + exclusive prefix
    int node = b * 256 + t;
    if (node < N) {
        rowptr[node] = rp;
        cnt[node]    = v;
        dinv[node]   = rsqrtf((float)v + 1.0f);   // +1 self loop
    }
    cur[t] = rp;
    __syncthreads();
    for (int s = s0 + t; s < s1; s += 256) {
        unsigned int p = tmp[s];
        int q = atomicAdd(&cur[(p >> 17) & 255], 1);
        csrc[q] = (int)(p & 0x1FFFFu);
    }
}

// --- one wave per node, 16 groups of 4 lanes; uint4 (16B) per lane ---------
// fp8 row = 4 uint4; byte b of uint s = channel s + 16*b.
// lane = grp*4 + q: holds uints 4q..4q+3 -> channels {4q+i+16b}.
__global__ __launch_bounds__(256) void k_agg(const int* __restrict__ rowptr,
        const int* __restrict__ cnt, const int* __restrict__ csrc,
        const uint4* __restrict__ hp, float* __restrict__ acc, int N) {
    int w = (blockIdx.x * 256 + threadIdx.x) >> 6;
    int lane = threadIdx.x & 63;
    if (w >= N) return;
    int grp = lane >> 2, q = lane & 3;
    int rs = rowptr[w], re = rs + cnt[w];
    f32x2 A0 = {0,0}, A1 = {0,0}, A2 = {0,0}, A3 = {0,0};  // {4q+i, 4q+i+16}
    f32x2 B0 = {0,0}, B1 = {0,0}, B2 = {0,0}, B3 = {0,0};  // {+32, +48}
    if (grp == 0) {                                         // self loop once
        uint4 v = hp[((size_t)w << 2) + q];
        A0 += __builtin_amdgcn_cvt_pk_f32_fp8((int)v.x, false);
        B0 += __builtin_amdgcn_cvt_pk_f32_fp8((int)v.x, true);
        A1 += __builtin_amdgcn_cvt_pk_f32_fp8((int)v.y, false);
        B1 += __builtin_amdgcn_cvt_pk_f32_fp8((int)v.y, true);
        A2 += __builtin_amdgcn_cvt_pk_f32_fp8((int)v.z, false);
        B2 += __builtin_amdgcn_cvt_pk_f32_fp8((int)v.z, true);
        A3 += __builtin_amdgcn_cvt_pk_f32_fp8((int)v.w, false);
        B3 += __builtin_amdgcn_cvt_pk_f32_fp8((int)v.w, true);
    }
    int e = rs + grp;
    for (; e + 16 < re; e += 32) {       // 32 edges in flight per wave
        int u0 = csrc[e];
        int u1 = csrc[e + 16];
        uint4 v0 = hp[((size_t)u0 << 2) + q];
        uint4 v1 = hp[((size_t)u1 << 2) + q];
        A0 += __builtin_amdgcn_cvt_pk_f32_fp8((int)v0.x, false);
        B0 += __builtin_amdgcn_cvt_pk_f32_fp8((int)v0.x, true);
        A1 += __builtin_amdgcn_cvt_pk_f32_fp8((int)v0.y, false);
        B1 += __builtin_amdgcn_cvt_pk_f32_fp8((int)v0.y, true);
        A2 += __builtin_amdgcn_cvt_pk_f32_fp8((int)v0.z, false);
        B2 += __builtin_amdgcn_cvt_pk_f32_fp8((int)v0.z, true);
        A3 += __builtin_amdgcn_cvt_pk_f32_fp8((int)v0.w, false);
        B3 += __builtin_amdgcn_cvt_pk_f32_fp8((int)v0.w, true);
        A0 += __builtin_amdgcn_cvt_pk_f32_fp8((int)v1.x, false);
        B0 += __builtin_amdgcn_cvt_pk_f32_fp8((int)v1.x, true);
        A1 += __builtin_amdgcn_cvt_pk_f32_fp8((int)v1.y, false);
        B1 += __builtin_amdgcn_cvt_pk_f32_fp8((int)v1.y, true);
        A2 += __builtin_amdgcn_cvt_pk_f32_fp8((int)v1.z, false);
        B2 += __builtin_amdgcn_cvt_pk_f32_fp8((int)v1.z, true);
        A3 += __builtin_amdgcn_cvt_pk_f32_fp8((int)v1.w, false);
        B3 += __builtin_amdgcn_cvt_pk_f32_fp8((int)v1.w, true);
    }
    if (e < re) {                         // tail: <=16 edges, one iteration
        int u = csrc[e];
        uint4 v = hp[((size_t)u << 2) + q];
        A0 += __builtin_amdgcn_cvt_pk_f32_fp8((int)v.x, false);
        B0 += __builtin_amdgcn_cvt_pk_f32_fp8((int)v.x, true);
        A1 += __builtin_amdgcn_cvt_pk_f32_fp8((int)v.y, false);
        B1 += __builtin_amdgcn_cvt_pk_f32_fp8((int)v.y, true);
        A2 += __builtin_amdgcn_cvt_pk_f32_fp8((int)v.z, false);
        B2 += __builtin_amdgcn_cvt_pk_f32_fp8((int)v.z, true);
        A3 += __builtin_amdgcn_cvt_pk_f32_fp8((int)v.w, false);
        B3 += __builtin_amdgcn_cvt_pk_f32_fp8((int)v.w, true);
    }
    // reduce across the 16 groups (lanes with equal q)
    #pragma unroll
    for (int o = 4; o < 64; o <<= 1) {
        f32x2 t0, t1, t2, t3, t4, t5, t6, t7;
        t0[0] = __shfl_xor(A0[0], o, 64); t0[1] = __shfl_xor(A0[1], o, 64);
        t1[0] = __shfl_xor(A1[0], o, 64); t1[1] = __shfl_xor(A1[1], o, 64);
        t2[0] = __shfl_xor(A2[0], o, 64); t2[1] = __shfl_xor(A2[1], o, 64);
        t3[0] = __shfl_xor(A3[0], o, 64); t3[1] = __shfl_xor(A3[1], o, 64);
        t4[0] = __shfl_xor(B0[0], o, 64); t4[1] = __shfl_xor(B0[1], o, 64);
        t5[0] = __shfl_xor(B1[0], o, 64); t5[1] = __shfl_xor(B1[1], o, 64);
        t6[0] = __shfl_xor(B2[0], o, 64); t6[1] = __shfl_xor(B2[1], o, 64);
        t7[0] = __shfl_xor(B3[0], o, 64); t7[1] = __shfl_xor(B3[1], o, 64);
        A0 += t0; A1 += t1; A2 += t2; A3 += t3;
        B0 += t4; B1 += t5; B2 += t6; B3 += t7;
    }
    if (grp == 0) {
        float* op = acc + ((size_t)w << 6);
        *(float4*)(op + q * 4)      = make_float4(A0[0], A1[0], A2[0], A3[0]);
        *(float4*)(op + 16 + q * 4) = make_float4(A0[1], A1[1], A2[1], A3[1]);
        *(float4*)(op + 32 + q * 4) = make_float4(B0[0], B1[0], B2[0], B3[0]);
        *(float4*)(op + 48 + q * 4) = make_float4(B0[1], B1[1], B2[1], B3[1]);
    }
}

// hs8 = fp8(dinv * (x @ W1)) via MFMA; x: N x 128 fp32, W1: 128 x 64
__global__ __launch_bounds__(256) void k_xform1(const float* __restrict__ x,
        const float* __restrict__ W1, const float* __restrict__ dinv,
        unsigned int* __restrict__ hs, int N, int ntiles) {
    int t = threadIdx.x;
    int lane = t & 63, wid = t >> 6;
    int r16 = lane & 15, kg = lane >> 4;
    half8 bf[4][4];                       // [coltile][ktile]
    #pragma unroll
    for (int ct = 0; ct < 4; ++ct)
        #pragma unroll
        for (int kt = 0; kt < 4; ++kt) {
            const float* wp = W1 + (kt * 32 + kg * 8) * 64 + ct * 16 + r16;
            half8 h;
            #pragma unroll
            for (int j = 0; j < 8; ++j) h[j] = (_Float16)wp[j * 64];
            bf[ct][kt] = h;
        }
    int wtile = blockIdx.x * 4 + wid;
    int nw = gridDim.x * 4;
    for (int tile = wtile; tile < ntiles; tile += nw) {
        int v0 = tile * 16;
        int rowA = min(v0 + r16, N - 1);
        const float* xp = x + (size_t)rowA * 128 + kg * 8;
        half8 af[4];
        #pragma unroll
        for (int kt = 0; kt < 4; ++kt) {
            float4 p = *(const float4*)(xp + kt * 32);
            float4 q = *(const float4*)(xp + kt * 32 + 4);
            half8 a;
            a[0] = (_Float16)p.x; a[1] = (_Float16)p.y;
            a[2] = (_Float16)p.z; a[3] = (_Float16)p.w;
            a[4] = (_Float16)q.x; a[5] = (_Float16)q.y;
            a[6] = (_Float16)q.z; a[7] = (_Float16)q.w;
            af[kt] = a;
        }
        f32x4 acc0 = {0,0,0,0}, acc1 = {0,0,0,0}, acc2 = {0,0,0,0}, acc3 = {0,0,0,0};
        #pragma unroll
        for (int kt = 0; kt < 4; ++kt) {
            acc0 = __builtin_amdgcn_mfma_f32_16x16x32_f16(af[kt], bf[0][kt], acc0, 0, 0, 0);
            acc1 = __builtin_amdgcn_mfma_f32_16x16x32_f16(af[kt], bf[1][kt], acc1, 0, 0, 0);
            acc2 = __builtin_amdgcn_mfma_f32_16x16x32_f16(af[kt], bf[2][kt], acc2, 0, 0, 0);
            acc3 = __builtin_amdgcn_mfma_f32_16x16x32_f16(af[kt], bf[3][kt], acc3, 0, 0, 0);
        }
        #pragma unroll
        for (int r = 0; r < 4; ++r) {
            int node = v0 + kg * 4 + r;
            if (node < N) {
                float d = dinv[node];
                int pk = __builtin_amdgcn_cvt_pk_fp8_f32(d * acc0[r], d * acc1[r], 0, false);
                pk     = __builtin_amdgcn_cvt_pk_fp8_f32(d * acc2[r], d * acc3[r], pk, true);
                hs[((size_t)node << 4) + r16] = (unsigned int)pk;
            }
        }
    }
}

// a = relu(dinv*acc + b1); hs2 = fp8(dinv * (a @ W2)) via MFMA; W2: 64 x 64
__global__ __launch_bounds__(256) void k_xform2(const float* __restrict__ acc_in,
        const float* __restrict__ W2, const float* __restrict__ b1,
        const float* __restrict__ dinv, unsigned int* __restrict__ hs2, int N, int ntiles) {
    int t = threadIdx.x;
    int lane = t & 63, wid = t >> 6;
    int r16 = lane & 15, kg = lane >> 4;
    half8 bf[4][2];
    #pragma unroll
    for (int ct = 0; ct < 4; ++ct)
        #pragma unroll
        for (int kt = 0; kt < 2; ++kt) {
            const float* wp = W2 + (kt * 32 + kg * 8) * 64 + ct * 16 + r16;
            half8 h;
            #pragma unroll
            for (int j = 0; j < 8; ++j) h[j] = (_Float16)wp[j * 64];
            bf[ct][kt] = h;
        }
    float b1r[2][8];
    #pragma unroll
    for (int kt = 0; kt < 2; ++kt)
        #pragma unroll
        for (int j = 0; j < 8; ++j) b1r[kt][j] = b1[kt * 32 + kg * 8 + j];
    int wtile = blockIdx.x * 4 + wid;
    int nw = gridDim.x * 4;
    for (int tile = wtile; tile < ntiles; tile += nw) {
        int v0 = tile * 16;
        int rowA = min(v0 + r16, N - 1);
        float da = dinv[rowA];
        const float* ap = acc_in + ((size_t)rowA << 6) + kg * 8;
        half8 af[2];
        #pragma unroll
        for (int kt = 0; kt < 2; ++kt) {
            float4 p = *(const float4*)(ap + kt * 32);
            float4 q = *(const float4*)(ap + kt * 32 + 4);
            half8 a;
            a[0] = (_Float16)fmaxf(fmaf(da, p.x, b1r[kt][0]), 0.f);
            a[1] = (_Float16)fmaxf(fmaf(da, p.y, b1r[kt][1]), 0.f);
            a[2] = (_Float16)fmaxf(fmaf(da, p.z, b1r[kt][2]), 0.f);
            a[3] = (_Float16)fmaxf(fmaf(da, p.w, b1r[kt][3]), 0.f);
            a[4] = (_Float16)fmaxf(fmaf(da, q.x, b1r[kt][4]), 0.f);
            a[5] = (_Float16)fmaxf(fmaf(da, q.y, b1r[kt][5]), 0.f);
            a[6] = (_Float16)fmaxf(fmaf(da, q.z, b1r[kt][6]), 0.f);
            a[7] = (_Float16)fmaxf(fmaf(da, q.w, b1r[kt][7]), 0.f);
            af[kt] = a;
        }
        f32x4 acc0 = {0,0,0,0}, acc1 = {0,0,0,0}, acc2 = {0,0,0,0}, acc3 = {0,0,0,0};
        #pragma unroll
        for (int kt = 0; kt < 2; ++kt) {
            acc0 = __builtin_amdgcn_mfma_f32_16x16x32_f16(af[kt], bf[0][kt], acc0, 0, 0, 0);
            acc1 = __builtin_amdgcn_mfma_f32_16x16x32_f16(af[kt], bf[1][kt], acc1, 0, 0, 0);
            acc2 = __builtin_amdgcn_mfma_f32_16x16x32_f16(af[kt], bf[2][kt], acc2, 0, 0, 0);
            acc3 = __builtin_amdgcn_mfma_f32_16x16x32_f16(af[kt], bf[3][kt], acc3, 0, 0, 0);
        }
        #pragma unroll
        for (int r = 0; r < 4; ++r) {
            int node = v0 + kg * 4 + r;
            if (node < N) {
                float d = dinv[node];
                int pk = __builtin_amdgcn_cvt_pk_fp8_f32(d * acc0[r], d * acc1[r], 0, false);
                pk     = __builtin_amdgcn_cvt_pk_fp8_f32(d * acc2[r], d * acc3[r], pk, true);
                hs2[((size_t)node << 4) + r16] = (unsigned int)pk;
            }
        }
    }
}

// a = relu(dinv*acc2 + b2); z = a @ Wf + bf; out = log_softmax(z) via MFMA.
__global__ __launch_bounds__(256) void k_final(const float* __restrict__ acc2,
        const float* __restrict__ Wf, const float* __restrict__ b2,
        const float* __restrict__ bf, const float* __restrict__ dinv,
        float* __restrict__ out, int N, int ntiles) {
    int t = threadIdx.x;
    int lane = t & 63, wid = t >> 6;
    int r16 = lane & 15, kg = lane >> 4;
    half8 bfr[3][2];
    #pragma unroll
    for (int ct = 0; ct < 3; ++ct)
        #pragma unroll
        for (int kt = 0; kt < 2; ++kt) {
            int col = ct * 16 + r16;
            half8 h;
            #pragma unroll
            for (int j = 0; j < 8; ++j) {
                int k = kt * 32 + kg * 8 + j;
                h[j] = (col < 40) ? (_Float16)Wf[k * 40 + col] : (_Float16)0.f;
            }
            bfr[ct][kt] = h;
        }
    float b2r[2][8];
    #pragma unroll
    for (int kt = 0; kt < 2; ++kt)
        #pragma unroll
        for (int j = 0; j < 8; ++j) b2r[kt][j] = b2[kt * 32 + kg * 8 + j];
    float bf0 = bf[r16];
    float bf1 = bf[16 + r16];
    float bf2 = (r16 < 8) ? bf[32 + r16] : 0.f;
    int wtile = blockIdx.x * 4 + wid;
    int nw = gridDim.x * 4;
    for (int tile = wtile; tile < ntiles; tile += nw) {
        int v0 = tile * 16;
        int rowA = min(v0 + r16, N - 1);
        float da = dinv[rowA];
        const float* ap = acc2 + ((size_t)rowA << 6) + kg * 8;
        half8 af[2];
        #pragma unroll
        for (int kt = 0; kt < 2; ++kt) {
            float4 p = *(const float4*)(ap + kt * 32);
            float4 q = *(const float4*)(ap + kt * 32 + 4);
            half8 a;
            a[0] = (_Float16)fmaxf(fmaf(da, p.x, b2r[kt][0]), 0.f);
            a[1] = (_Float16)fmaxf(fmaf(da, p.y, b2r[kt][1]), 0.f);
            a[2] = (_Float16)fmaxf(fmaf(da, p.z, b2r[kt][2]), 0.f);
            a[3] = (_Float16)fmaxf(fmaf(da, p.w, b2r[kt][3]), 0.f);
            a[4] = (_Float16)fmaxf(fmaf(da, q.x, b2r[kt][4]), 0.f);
            a[5] = (_Float16)fmaxf(fmaf(da, q.y, b2r[kt][5]), 0.f);
            a[6] = (_Float16)fmaxf(fmaf(da, q.z, b2r[kt][6]), 0.f);
            a[7] = (_Float16)fmaxf(fmaf(da, q.w, b2r[kt][7]), 0.f);
            af[kt] = a;
        }
        f32x4 a0 = {0,0,0,0}, a1 = {0,0,0,0}, a2 = {0,0,0,0};
        #pragma unroll
        for (int kt = 0; kt < 2; ++kt) {
            a0 = __builtin_amdgcn_mfma_f32_16x16x32_f16(af[kt], bfr[0][kt], a0, 0, 0, 0);
            a1 = __builtin_amdgcn_mfma_f32_16x16x32_f16(af[kt], bfr[1][kt], a1, 0, 0, 0);
            a2 = __builtin_amdgcn_mfma_f32_16x16x32_f16(af[kt], bfr[2][kt], a2, 0, 0, 0);
        }
        #pragma unroll
        for (int r = 0; r < 4; ++r) {
            float z0 = a0[r] + bf0;
            float z1 = a1[r] + bf1;
            float z2 = (r16 < 8) ? (a2[r] + bf2) : -INFINITY;
            float m = fmaxf(fmaxf(z0, z1), z2);
            #pragma unroll
            for (int o = 8; o; o >>= 1) m = fmaxf(m, __shfl_xor(m, o, 64));
            float s = expf(z0 - m) + expf(z1 - m) + ((r16 < 8) ? expf(z2 - m) : 0.f);
            #pragma unroll
            for (int o = 8; o; o >>= 1) s += __shfl_xor(s, o, 64);
            float ls = m + logf(s);
            int node = v0 + kg * 4 + r;
            if (node < N) {
                float* op = out + (size_t)node * 40;
                op[r16]      = z0 - ls;
                op[16 + r16] = z1 - ls;
                if (r16 < 8) op[32 + r16] = z2 - ls;
            }
        }
    }
}

extern "C" void kernel_launch(void* const* d_in, const int* in_sizes, int n_in,
                              void* d_out, int out_size, void* d_ws, size_t ws_size,
                              hipStream_t stream) {
    const float* x  = (const float*)d_in[0];
    const int*   ei = (const int*)d_in[1];   // [2, E]: row 0 = src, row 1 = dst
    const float* W1 = (const float*)d_in[2];
    const float* b1 = (const float*)d_in[3];
    const float* W2 = (const float*)d_in[4];
    const float* b2 = (const float*)d_in[5];
    const float* Wf = (const float*)d_in[6];
    const float* bf = (const float*)d_in[7];
    float* out = (float*)d_out;

    const int N = in_sizes[0] / 128;
    const int E = in_sizes[1] / 2;
    const int* src = ei;
    const int* dst = ei + E;
    const int NB = (N + 255) >> 8;           // coarse buckets (256 nodes each)

    auto align = [](size_t s) { return (s + 255) & ~(size_t)255; };
    char* ws = (char*)d_ws;
    size_t o = 0;
    int*   rowptr  = (int*)(ws + o);   o += align((size_t)N * 4);
    int*   cnt     = (int*)(ws + o);   o += align((size_t)N * 4);
    float* dinv    = (float*)(ws + o); o += align((size_t)N * 4);
    int*   cursor1 = (int*)(ws + o);   o += align(512 * 4);
    int*   csrc    = (int*)(ws + o);   o += align((size_t)NB * CAP * 4);
    unsigned int* B1 = (unsigned int*)(ws + o); o += align((size_t)N * 64);  // hs fp8
    float*  B2     = (float*)(ws + o);  o += align((size_t)N * 64 * 4);      // acc
    unsigned int* tmp = (unsigned int*)B2;   // alias: tmp dead before k_agg writes B2

    int blkT  = (E + T1 - 1) / T1;
    int ntile = (N + 15) / 16;
    int gX = 512;                     // persistent MFMA blocks (4 waves each)

    k_init <<<1,    512, 0, stream>>>(cursor1, NB);
    k_pass1<<<blkT, 256, 0, stream>>>(src, dst, cursor1, tmp, E, NB);
    k_p2   <<<NB,   256, 0, stream>>>(tmp, cursor1, rowptr, cnt, csrc, dinv, N);

    int blkAgg = (N * 64 + 255) / 256;  // one wave per node
    k_xform1<<<gX, 256, 0, stream>>>(x, W1, dinv, B1, N, ntile);
    k_agg   <<<blkAgg, 256, 0, stream>>>(rowptr, cnt, csrc, (const uint4*)B1, B2, N);
    k_xform2<<<gX, 256, 0, stream>>>(B2, W2, b1, dinv, B1, N, ntile);
    k_agg   <<<blkAgg, 256, 0, stream>>>(rowptr, cnt, csrc, (const uint4*)B1, B2, N);
    k_final <<<gX, 256, 0, stream>>>(B2, Wf, b2, bf, dinv, out, N, ntile);
}

// Round 14
// 213.870 us; speedup vs baseline: 1.1630x; 1.1630x over previous
//
#include <hip/hip_runtime.h>
#include <hip/hip_fp16.h>
#include <cstdint>
#include <cstddef>
#include <cmath>

// ---------------------------------------------------------------------------
// GCN via CSR aggregation:
//   binning: fixed-capacity dst-buckets (128 nodes, CAP=6144, 32-sigma) ->
//            k_pass1 packs edges into tmp runs -> k_p2x builds
//            rowptr/cnt/dinv + csrc AND runs the fused xform1 MFMA tail
//            (dinv in LDS) for its 128 nodes.
//   agg: R10-proven: one wave per node, 4 lane-groups of 16, 4B/lane fp8
//        gathers, unroll-4 (16 edges in flight), 8-shfl epilogue. ~54.7us.
//   xform2/final: MFMA 16x16x32 f16 persistent blocks, fp8 pack/unpack via
//   v_cvt_pk_fp8_f32 / v_cvt_pk_f32_fp8 (byte b of uint s = channel s+16b).
//   tmp aliases B2 (dead before first k_agg write).
// ---------------------------------------------------------------------------

#define T1  4096    // edges per pass-1 tile
#define BSH 7       // 128-node buckets
#define CAP 6144    // bucket capacity (avg 4092, sigma ~64)

typedef _Float16 half8 __attribute__((ext_vector_type(8)));
typedef float f32x4 __attribute__((ext_vector_type(4)));
typedef float f32x2 __attribute__((ext_vector_type(2)));

__global__ __launch_bounds__(512) void k_init(int* __restrict__ cursor1, int NB) {
    int t = threadIdx.x;
    for (int i = t; i < NB; i += 512) cursor1[i] = i * CAP;
}

__global__ __launch_bounds__(256) void k_pass1(const int* __restrict__ src,
        const int* __restrict__ dst, int* __restrict__ cursor1,
        unsigned int* __restrict__ tmp, int E, int NB) {
    __shared__ unsigned int pack[T1];                 // 16 KB
    __shared__ unsigned short bkt[T1];                //  8 KB
    __shared__ int h[1024], hs_[1024], gbase[1024];   // 12 KB
    int t = threadIdx.x;
    for (int i = t; i < 1024; i += 256) h[i] = 0;
    __syncthreads();
    int base = blockIdx.x * T1;
    int n = min(T1, E - base);
    unsigned int pk[16];
    int bl[16];
    #pragma unroll
    for (int i = 0; i < 16; ++i) {
        int idx = i * 256 + t;
        if (idx < n) {
            int s_ = src[base + idx], d = dst[base + idx];
            int b = d >> BSH;
            pk[i] = (unsigned int)s_ | ((unsigned int)(d & 127) << 17);
            int lo = atomicAdd(&h[b], 1);
            bl[i] = (b << 13) | lo;
        } else bl[i] = -1;
    }
    __syncthreads();
    #pragma unroll
    for (int i = 0; i < 4; ++i) hs_[t + i * 256] = h[t + i * 256];
    __syncthreads();
    for (int st = 1; st < 1024; st <<= 1) {
        int tp[4];
        #pragma unroll
        for (int i = 0; i < 4; ++i) {
            int idx = t + i * 256;
            tp[i] = (idx >= st) ? hs_[idx - st] : 0;
        }
        __syncthreads();
        #pragma unroll
        for (int i = 0; i < 4; ++i) hs_[t + i * 256] += tp[i];
        __syncthreads();
    }
    for (int i = t; i < NB; i += 256)
        gbase[i] = h[i] ? atomicAdd(&cursor1[i], h[i]) : 0;
    __syncthreads();
    #pragma unroll
    for (int i = 0; i < 16; ++i) {
        if (bl[i] >= 0) {
            int b = bl[i] >> 13, lo = bl[i] & 8191;
            int slot = hs_[b] - h[b] + lo;
            pack[slot] = pk[i];
            bkt[slot]  = (unsigned short)b;
        }
    }
    __syncthreads();
    for (int s_ = t; s_ < n; s_ += 256) {
        int b = bkt[s_];
        tmp[gbase[b] + (s_ - (hs_[b] - h[b]))] = pack[s_];
    }
}

// per-bucket: histogram -> scan -> rowptr/cnt/dinv -> csrc scatter,
// then fused xform1 MFMA tail: hs8 = fp8(dinv * (x @ W1)) for the 128 nodes.
__global__ __launch_bounds__(256) void k_p2x(const unsigned int* __restrict__ tmp,
        const int* __restrict__ cursor1, int* __restrict__ rowptr,
        int* __restrict__ cnt, int* __restrict__ csrc, float* __restrict__ dinv,
        const float* __restrict__ x, const float* __restrict__ W1,
        unsigned int* __restrict__ hs, int N) {
    __shared__ int c[128], cur[128];
    __shared__ float sdinv[128];
    int t = threadIdx.x, b = blockIdx.x;
    if (t < 128) c[t] = 0;
    __syncthreads();
    int s0 = b * CAP, s1 = cursor1[b];
    for (int s = s0 + t; s < s1; s += 256)
        atomicAdd(&c[(tmp[s] >> 17) & 127], 1);
    __syncthreads();
    int v = 0;
    if (t < 128) { v = c[t]; cur[t] = v; }
    __syncthreads();
    for (int st = 1; st < 128; st <<= 1) {
        int p = (t < 128 && t >= st) ? cur[t - st] : 0;
        __syncthreads();
        if (t < 128) cur[t] += p;
        __syncthreads();
    }
    int node = b * 128 + t;
    if (t < 128) {
        int rp = s0 + cur[t] - v;
        float dv = rsqrtf((float)v + 1.0f);   // +1 self loop
        sdinv[t] = dv;
        if (node < N) {
            rowptr[node] = rp;
            cnt[node]    = v;
            dinv[node]   = dv;
        }
        cur[t] = rp;
    }
    __syncthreads();
    for (int s = s0 + t; s < s1; s += 256) {
        unsigned int p = tmp[s];
        int q = atomicAdd(&cur[(p >> 17) & 127], 1);
        csrc[q] = (int)(p & 0x1FFFFu);
    }
    __syncthreads();
    // ---------------- fused xform1 MFMA tail ------------------------------
    int lane = t & 63, wid = t >> 6;
    int r16 = lane & 15, kg = lane >> 4;
    half8 bf[4][4];                       // [coltile][ktile]
    #pragma unroll
    for (int ct = 0; ct < 4; ++ct)
        #pragma unroll
        for (int kt = 0; kt < 4; ++kt) {
            const float* wp = W1 + (kt * 32 + kg * 8) * 64 + ct * 16 + r16;
            half8 h;
            #pragma unroll
            for (int j = 0; j < 8; ++j) h[j] = (_Float16)wp[j * 64];
            bf[ct][kt] = h;
        }
    #pragma unroll
    for (int lt2 = 0; lt2 < 2; ++lt2) {   // 2 tiles per wave (8 per block)
        int lt = wid * 2 + lt2;
        int v0 = b * 128 + lt * 16;
        int rowA = min(v0 + r16, N - 1);
        const float* xp = x + (size_t)rowA * 128 + kg * 8;
        half8 af[4];
        #pragma unroll
        for (int kt = 0; kt < 4; ++kt) {
            float4 p = *(const float4*)(xp + kt * 32);
            float4 q = *(const float4*)(xp + kt * 32 + 4);
            half8 a;
            a[0] = (_Float16)p.x; a[1] = (_Float16)p.y;
            a[2] = (_Float16)p.z; a[3] = (_Float16)p.w;
            a[4] = (_Float16)q.x; a[5] = (_Float16)q.y;
            a[6] = (_Float16)q.z; a[7] = (_Float16)q.w;
            af[kt] = a;
        }
        f32x4 acc0 = {0,0,0,0}, acc1 = {0,0,0,0}, acc2 = {0,0,0,0}, acc3 = {0,0,0,0};
        #pragma unroll
        for (int kt = 0; kt < 4; ++kt) {
            acc0 = __builtin_amdgcn_mfma_f32_16x16x32_f16(af[kt], bf[0][kt], acc0, 0, 0, 0);
            acc1 = __builtin_amdgcn_mfma_f32_16x16x32_f16(af[kt], bf[1][kt], acc1, 0, 0, 0);
            acc2 = __builtin_amdgcn_mfma_f32_16x16x32_f16(af[kt], bf[2][kt], acc2, 0, 0, 0);
            acc3 = __builtin_amdgcn_mfma_f32_16x16x32_f16(af[kt], bf[3][kt], acc3, 0, 0, 0);
        }
        #pragma unroll
        for (int r = 0; r < 4; ++r) {
            int nd = v0 + kg * 4 + r;
            if (nd < N) {
                float d = sdinv[lt * 16 + kg * 4 + r];
                int pk = __builtin_amdgcn_cvt_pk_fp8_f32(d * acc0[r], d * acc1[r], 0, false);
                pk     = __builtin_amdgcn_cvt_pk_fp8_f32(d * acc2[r], d * acc3[r], pk, true);
                hs[((size_t)nd << 4) + r16] = (unsigned int)pk;
            }
        }
    }
}

// --- R10-proven agg: one wave per node, 4 lane-groups of 16, unroll-4 ------
// fp8 row = 16 uints; byte b of uint s = channel s + 16*b.
__global__ __launch_bounds__(256) void k_agg(const int* __restrict__ rowptr,
        const int* __restrict__ cnt, const int* __restrict__ csrc,
        const unsigned int* __restrict__ hp, float* __restrict__ acc, int N) {
    int w = (blockIdx.x * 256 + threadIdx.x) >> 6;
    int lane = threadIdx.x & 63;
    if (w >= N) return;
    int grp = lane >> 4, sub = lane & 15;
    int rs = rowptr[w], re = rs + cnt[w];
    float a0 = 0.f, a1 = 0.f, a2 = 0.f, a3 = 0.f;
    if (grp == 0) {                                     // self loop, once
        unsigned v = hp[((size_t)w << 4) + sub];
        f32x2 lo = __builtin_amdgcn_cvt_pk_f32_fp8((int)v, false);
        f32x2 hi = __builtin_amdgcn_cvt_pk_f32_fp8((int)v, true);
        a0 = lo[0]; a1 = lo[1]; a2 = hi[0]; a3 = hi[1];
    }
    int e = rs + grp;
    for (; e + 12 < re; e += 16) {
        int u0 = csrc[e], u1 = csrc[e + 4], u2 = csrc[e + 8], u3 = csrc[e + 12];
        unsigned v0 = hp[((size_t)u0 << 4) + sub];
        unsigned v1 = hp[((size_t)u1 << 4) + sub];
        unsigned v2 = hp[((size_t)u2 << 4) + sub];
        unsigned v3 = hp[((size_t)u3 << 4) + sub];
        f32x2 l0 = __builtin_amdgcn_cvt_pk_f32_fp8((int)v0, false);
        f32x2 h0 = __builtin_amdgcn_cvt_pk_f32_fp8((int)v0, true);
        f32x2 l1 = __builtin_amdgcn_cvt_pk_f32_fp8((int)v1, false);
        f32x2 h1 = __builtin_amdgcn_cvt_pk_f32_fp8((int)v1, true);
        f32x2 l2 = __builtin_amdgcn_cvt_pk_f32_fp8((int)v2, false);
        f32x2 h2 = __builtin_amdgcn_cvt_pk_f32_fp8((int)v2, true);
        f32x2 l3 = __builtin_amdgcn_cvt_pk_f32_fp8((int)v3, false);
        f32x2 h3 = __builtin_amdgcn_cvt_pk_f32_fp8((int)v3, true);
        a0 += l0[0]; a1 += l0[1]; a2 += h0[0]; a3 += h0[1];
        a0 += l1[0]; a1 += l1[1]; a2 += h1[0]; a3 += h1[1];
        a0 += l2[0]; a1 += l2[1]; a2 += h2[0]; a3 += h2[1];
        a0 += l3[0]; a1 += l3[1]; a2 += h3[0]; a3 += h3[1];
    }
    for (; e < re; e += 4) {
        unsigned v = hp[((size_t)csrc[e] << 4) + sub];
        f32x2 lo = __builtin_amdgcn_cvt_pk_f32_fp8((int)v, false);
        f32x2 hi = __builtin_amdgcn_cvt_pk_f32_fp8((int)v, true);
        a0 += lo[0]; a1 += lo[1]; a2 += hi[0]; a3 += hi[1];
    }
    a0 += __shfl_xor(a0, 16, 64); a0 += __shfl_xor(a0, 32, 64);
    a1 += __shfl_xor(a1, 16, 64); a1 += __shfl_xor(a1, 32, 64);
    a2 += __shfl_xor(a2, 16, 64); a2 += __shfl_xor(a2, 32, 64);
    a3 += __shfl_xor(a3, 16, 64); a3 += __shfl_xor(a3, 32, 64);
    if (grp == 0) {
        float* op = acc + ((size_t)w << 6) + sub;
        op[0]  = a0;
        op[16] = a1;
        op[32] = a2;
        op[48] = a3;
    }
}

// a = relu(dinv*acc + b1); hs2 = fp8(dinv * (a @ W2)) via MFMA; W2: 64 x 64
__global__ __launch_bounds__(256) void k_xform2(const float* __restrict__ acc_in,
        const float* __restrict__ W2, const float* __restrict__ b1,
        const float* __restrict__ dinv, unsigned int* __restrict__ hs2, int N, int ntiles) {
    int t = threadIdx.x;
    int lane = t & 63, wid = t >> 6;
    int r16 = lane & 15, kg = lane >> 4;
    half8 bf[4][2];
    #pragma unroll
    for (int ct = 0; ct < 4; ++ct)
        #pragma unroll
        for (int kt = 0; kt < 2; ++kt) {
            const float* wp = W2 + (kt * 32 + kg * 8) * 64 + ct * 16 + r16;
            half8 h;
            #pragma unroll
            for (int j = 0; j < 8; ++j) h[j] = (_Float16)wp[j * 64];
            bf[ct][kt] = h;
        }
    float b1r[2][8];
    #pragma unroll
    for (int kt = 0; kt < 2; ++kt)
        #pragma unroll
        for (int j = 0; j < 8; ++j) b1r[kt][j] = b1[kt * 32 + kg * 8 + j];
    int wtile = blockIdx.x * 4 + wid;
    int nw = gridDim.x * 4;
    for (int tile = wtile; tile < ntiles; tile += nw) {
        int v0 = tile * 16;
        int rowA = min(v0 + r16, N - 1);
        float da = dinv[rowA];
        const float* ap = acc_in + ((size_t)rowA << 6) + kg * 8;
        half8 af[2];
        #pragma unroll
        for (int kt = 0; kt < 2; ++kt) {
            float4 p = *(const float4*)(ap + kt * 32);
            float4 q = *(const float4*)(ap + kt * 32 + 4);
            half8 a;
            a[0] = (_Float16)fmaxf(fmaf(da, p.x, b1r[kt][0]), 0.f);
            a[1] = (_Float16)fmaxf(fmaf(da, p.y, b1r[kt][1]), 0.f);
            a[2] = (_Float16)fmaxf(fmaf(da, p.z, b1r[kt][2]), 0.f);
            a[3] = (_Float16)fmaxf(fmaf(da, p.w, b1r[kt][3]), 0.f);
            a[4] = (_Float16)fmaxf(fmaf(da, q.x, b1r[kt][4]), 0.f);
            a[5] = (_Float16)fmaxf(fmaf(da, q.y, b1r[kt][5]), 0.f);
            a[6] = (_Float16)fmaxf(fmaf(da, q.z, b1r[kt][6]), 0.f);
            a[7] = (_Float16)fmaxf(fmaf(da, q.w, b1r[kt][7]), 0.f);
            af[kt] = a;
        }
        f32x4 acc0 = {0,0,0,0}, acc1 = {0,0,0,0}, acc2 = {0,0,0,0}, acc3 = {0,0,0,0};
        #pragma unroll
        for (int kt = 0; kt < 2; ++kt) {
            acc0 = __builtin_amdgcn_mfma_f32_16x16x32_f16(af[kt], bf[0][kt], acc0, 0, 0, 0);
            acc1 = __builtin_amdgcn_mfma_f32_16x16x32_f16(af[kt], bf[1][kt], acc1, 0, 0, 0);
            acc2 = __builtin_amdgcn_mfma_f32_16x16x32_f16(af[kt], bf[2][kt], acc2, 0, 0, 0);
            acc3 = __builtin_amdgcn_mfma_f32_16x16x32_f16(af[kt], bf[3][kt], acc3, 0, 0, 0);
        }
        #pragma unroll
        for (int r = 0; r < 4; ++r) {
            int node = v0 + kg * 4 + r;
            if (node < N) {
                float d = dinv[node];
                int pk = __builtin_amdgcn_cvt_pk_fp8_f32(d * acc0[r], d * acc1[r], 0, false);
                pk     = __builtin_amdgcn_cvt_pk_fp8_f32(d * acc2[r], d * acc3[r], pk, true);
                hs2[((size_t)node << 4) + r16] = (unsigned int)pk;
            }
        }
    }
}

// a = relu(dinv*acc2 + b2); z = a @ Wf + bf; out = log_softmax(z) via MFMA.
__global__ __launch_bounds__(256) void k_final(const float* __restrict__ acc2,
        const float* __restrict__ Wf, const float* __restrict__ b2,
        const float* __restrict__ bf, const float* __restrict__ dinv,
        float* __restrict__ out, int N, int ntiles) {
    int t = threadIdx.x;
    int lane = t & 63, wid = t >> 6;
    int r16 = lane & 15, kg = lane >> 4;
    half8 bfr[3][2];
    #pragma unroll
    for (int ct = 0; ct < 3; ++ct)
        #pragma unroll
        for (int kt = 0; kt < 2; ++kt) {
            int col = ct * 16 + r16;
            half8 h;
            #pragma unroll
            for (int j = 0; j < 8; ++j) {
                int k = kt * 32 + kg * 8 + j;
                h[j] = (col < 40) ? (_Float16)Wf[k * 40 + col] : (_Float16)0.f;
            }
            bfr[ct][kt] = h;
        }
    float b2r[2][8];
    #pragma unroll
    for (int kt = 0; kt < 2; ++kt)
        #pragma unroll
        for (int j = 0; j < 8; ++j) b2r[kt][j] = b2[kt * 32 + kg * 8 + j];
    float bf0 = bf[r16];
    float bf1 = bf[16 + r16];
    float bf2 = (r16 < 8) ? bf[32 + r16] : 0.f;
    int wtile = blockIdx.x * 4 + wid;
    int nw = gridDim.x * 4;
    for (int tile = wtile; tile < ntiles; tile += nw) {
        int v0 = tile * 16;
        int rowA = min(v0 + r16, N - 1);
        float da = dinv[rowA];
        const float* ap = acc2 + ((size_t)rowA << 6) + kg * 8;
        half8 af[2];
        #pragma unroll
        for (int kt = 0; kt < 2; ++kt) {
            float4 p = *(const float4*)(ap + kt * 32);
            float4 q = *(const float4*)(ap + kt * 32 + 4);
            half8 a;
            a[0] = (_Float16)fmaxf(fmaf(da, p.x, b2r[kt][0]), 0.f);
            a[1] = (_Float16)fmaxf(fmaf(da, p.y, b2r[kt][1]), 0.f);
            a[2] = (_Float16)fmaxf(fmaf(da, p.z, b2r[kt][2]), 0.f);
            a[3] = (_Float16)fmaxf(fmaf(da, p.w, b2r[kt][3]), 0.f);
            a[4] = (_Float16)fmaxf(fmaf(da, q.x, b2r[kt][4]), 0.f);
            a[5] = (_Float16)fmaxf(fmaf(da, q.y, b2r[kt][5]), 0.f);
            a[6] = (_Float16)fmaxf(fmaf(da, q.z, b2r[kt][6]), 0.f);
            a[7] = (_Float16)fmaxf(fmaf(da, q.w, b2r[kt][7]), 0.f);
            af[kt] = a;
        }
        f32x4 a0 = {0,0,0,0}, a1 = {0,0,0,0}, a2 = {0,0,0,0};
        #pragma unroll
        for (int kt = 0; kt < 2; ++kt) {
            a0 = __builtin_amdgcn_mfma_f32_16x16x32_f16(af[kt], bfr[0][kt], a0, 0, 0, 0);
            a1 = __builtin_amdgcn_mfma_f32_16x16x32_f16(af[kt], bfr[1][kt], a1, 0, 0, 0);
            a2 = __builtin_amdgcn_mfma_f32_16x16x32_f16(af[kt], bfr[2][kt], a2, 0, 0, 0);
        }
        #pragma unroll
        for (int r = 0; r < 4; ++r) {
            float z0 = a0[r] + bf0;
            float z1 = a1[r] + bf1;
            float z2 = (r16 < 8) ? (a2[r] + bf2) : -INFINITY;
            float m = fmaxf(fmaxf(z0, z1), z2);
            #pragma unroll
            for (int o = 8; o; o >>= 1) m = fmaxf(m, __shfl_xor(m, o, 64));
            float s = expf(z0 - m) + expf(z1 - m) + ((r16 < 8) ? expf(z2 - m) : 0.f);
            #pragma unroll
            for (int o = 8; o; o >>= 1) s += __shfl_xor(s, o, 64);
            float ls = m + logf(s);
            int node = v0 + kg * 4 + r;
            if (node < N) {
                float* op = out + (size_t)node * 40;
                op[r16]      = z0 - ls;
                op[16 + r16] = z1 - ls;
                if (r16 < 8) op[32 + r16] = z2 - ls;
            }
        }
    }
}

extern "C" void kernel_launch(void* const* d_in, const int* in_sizes, int n_in,
                              void* d_out, int out_size, void* d_ws, size_t ws_size,
                              hipStream_t stream) {
    const float* x  = (const float*)d_in[0];
    const int*   ei = (const int*)d_in[1];   // [2, E]: row 0 = src, row 1 = dst
    const float* W1 = (const float*)d_in[2];
    const float* b1 = (const float*)d_in[3];
    const float* W2 = (const float*)d_in[4];
    const float* b2 = (const float*)d_in[5];
    const float* Wf = (const float*)d_in[6];
    const float* bf = (const float*)d_in[7];
    float* out = (float*)d_out;

    const int N = in_sizes[0] / 128;
    const int E = in_sizes[1] / 2;
    const int* src = ei;
    const int* dst = ei + E;
    const int NB = (N + 127) >> BSH;         // 128-node buckets (<=1024)

    auto align = [](size_t s) { return (s + 255) & ~(size_t)255; };
    char* ws = (char*)d_ws;
    size_t o = 0;
    int*   rowptr  = (int*)(ws + o);   o += align((size_t)N * 4);
    int*   cnt     = (int*)(ws + o);   o += align((size_t)N * 4);
    float* dinv    = (float*)(ws + o); o += align((size_t)N * 4);
    int*   cursor1 = (int*)(ws + o);   o += align(1024 * 4);
    int*   csrc    = (int*)(ws + o);   o += align((size_t)NB * CAP * 4);
    unsigned int* B1 = (unsigned int*)(ws + o); o += align((size_t)N * 64);  // hs fp8
    float*  B2     = (float*)(ws + o);  o += align((size_t)N * 64 * 4);      // acc
    unsigned int* tmp = (unsigned int*)B2;   // alias: tmp dead before k_agg writes B2

    int blkT  = (E + T1 - 1) / T1;
    int ntile = (N + 15) / 16;
    int gX = 512;                     // persistent MFMA blocks (4 waves each)

    k_init <<<1,    512, 0, stream>>>(cursor1, NB);
    k_pass1<<<blkT, 256, 0, stream>>>(src, dst, cursor1, tmp, E, NB);
    k_p2x  <<<NB,   256, 0, stream>>>(tmp, cursor1, rowptr, cnt, csrc, dinv,
                                      x, W1, B1, N);

    int blkAgg = (N * 64 + 255) / 256;  // one wave per node
    k_agg   <<<blkAgg, 256, 0, stream>>>(rowptr, cnt, csrc, B1, B2, N);
    k_xform2<<<gX, 256, 0, stream>>>(B2, W2, b1, dinv, B1, N, ntile);
    k_agg   <<<blkAgg, 256, 0, stream>>>(rowptr, cnt, csrc, B1, B2, N);
    k_final <<<gX, 256, 0, stream>>>(B2, Wf, b2, bf, dinv, out, N, ntile);
}